// Round 1
// baseline (10755.223 us; speedup 1.0000x reference)
//
#include <hip/hip_runtime.h>
#include <hip/hip_bf16.h>

#define Bn 32
#define Sn 400
#define Tn 100
#define Vn 32000
#define OOVn 100
#define VEn 32100
#define En 512
#define Un 256
#define AUn 256
#define GPn 256
#define ENCn 512
#define Z4n 1024

typedef __attribute__((ext_vector_type(8))) short bf16x8;
typedef __attribute__((ext_vector_type(4))) float f32x4;
typedef unsigned short ushort_t;
typedef unsigned long long u64;

__device__ __forceinline__ float rcp_f(float x){ return __builtin_amdgcn_rcpf(x); }
// inf-safe tanh: 1 - 2/(e^{2x}+1)
__device__ __forceinline__ float tanh_fast(float x){
  float e2 = __expf(2.f*x);
  return 1.f - 2.f*rcp_f(e2 + 1.f);
}
__device__ __forceinline__ float sigmoid_f(float x){ return 1.f/(1.f+__expf(-x)); }
__device__ __forceinline__ ushort_t f2bf(float f){
  unsigned u = __float_as_uint(f);
  unsigned r = (u + 0x7FFFu + ((u>>16)&1u)) >> 16;   // RNE
  return (ushort_t)r;
}
__device__ __forceinline__ u64 shfl_xor_u64(u64 v, int m){
  unsigned lo = (unsigned)v, hi = (unsigned)(v>>32);
  lo = (unsigned)__shfl_xor((int)lo, m);
  hi = (unsigned)__shfl_xor((int)hi, m);
  return ((u64)hi<<32)|(u64)lo;
}

// ---------------- pre-loop kernels ----------------

__global__ __launch_bounds__(256) void k_init(const float* __restrict__ c0,
    float* __restrict__ c_state, float* __restrict__ cov){
  int idx = blockIdx.x*256 + threadIdx.x;
  if (idx < Bn*Un) c_state[idx] = c0[idx];
  if (idx < Bn*Sn) cov[idx] = 0.f;
}

__global__ __launch_bounds__(256) void k_gather(const int* __restrict__ gt,
    const float* __restrict__ emb, float* __restrict__ Xall){
  int r = blockIdx.x;                 // r = t*32 + b
  int t = r >> 5, b = r & 31;
  int tok = gt[b*Tn + t];
  const float* src = emb + (size_t)tok*En;
  float* dst = Xall + (size_t)r*En;
  for (int i = threadIdx.x; i < En; i += 256) dst[i] = src[i];
}

// Zx = Xall @ Wk + bias   [3200,512]@[512,1024], f32 tiled 64x64
__global__ __launch_bounds__(256) void k_zx(const float* __restrict__ X,
    const float* __restrict__ Wk, const float* __restrict__ bias, float* __restrict__ Zx){
  __shared__ float As[64][17];
  __shared__ float Bs[16][65];
  int r0 = blockIdx.x * 64;
  int c0 = blockIdx.y * 64;
  int tid = threadIdx.x;
  int ty = tid >> 4, tx = tid & 15;
  float acc[4][4] = {};
  for (int k0 = 0; k0 < En; k0 += 16){
    #pragma unroll
    for (int p = 0; p < 4; ++p){
      int row = (tid>>4) + p*16, kk = tid & 15;
      As[row][kk] = X[(size_t)(r0+row)*En + k0 + kk];
    }
    #pragma unroll
    for (int p = 0; p < 4; ++p){
      int kk = (tid>>6) + p*4, cc = tid & 63;
      Bs[kk][cc] = Wk[(size_t)(k0+kk)*Z4n + c0 + cc];
    }
    __syncthreads();
    #pragma unroll
    for (int kk = 0; kk < 16; ++kk){
      float av[4], bv[4];
      #pragma unroll
      for (int i=0;i<4;++i) av[i] = As[ty*4+i][kk];
      #pragma unroll
      for (int j=0;j<4;++j) bv[j] = Bs[kk][tx*4+j];
      #pragma unroll
      for (int i=0;i<4;++i)
        #pragma unroll
        for (int j=0;j<4;++j) acc[i][j] += av[i]*bv[j];
    }
    __syncthreads();
  }
  #pragma unroll
  for (int i=0;i<4;++i){
    int row = r0 + ty*4 + i;
    #pragma unroll
    for (int j=0;j<4;++j){
      int col = c0 + tx*4 + j;
      Zx[(size_t)row*Z4n + col] = acc[i][j] + bias[col];
    }
  }
}

// gpx[t,:] = x[t,b=0,:] @ gp_Wi + gp_bi
__global__ __launch_bounds__(256) void k_gpx(const float* __restrict__ Xall,
    const float* __restrict__ Wi, const float* __restrict__ bi, float* __restrict__ gpx){
  int t = blockIdx.x, j = threadIdx.x;
  const float* x = Xall + (size_t)(t*Bn + 0)*En;
  float acc = bi[j];
  for (int u = 0; u < En; ++u) acc += x[u]*Wi[u*GPn + j];
  gpx[t*GPn + j] = acc;
}

__global__ __launch_bounds__(256) void k_w2bf(const float* __restrict__ W2,
    ushort_t* __restrict__ W2b){
  size_t idx = ((size_t)blockIdx.x*256 + threadIdx.x)*8;
  float4 a = *(const float4*)(W2 + idx);
  float4 b = *(const float4*)(W2 + idx + 4);
  ushort_t o[8] = {f2bf(a.x),f2bf(a.y),f2bf(a.z),f2bf(a.w),
                   f2bf(b.x),f2bf(b.y),f2bf(b.z),f2bf(b.w)};
  *(uint4*)(W2b + idx) = *(const uint4*)o;
}

// ---------------- recurrent step device functions ----------------

// LSTM step: z = Zx[step] + h_prev@Wr ; gates -> h,c.  blk in [0,16): 16 h-cols each.
__device__ __forceinline__ void lstm_dev(int step, int blk, const float* __restrict__ hprev,
    const float* __restrict__ Zx, const float* __restrict__ Wr,
    float* __restrict__ hout, float* __restrict__ c_state, float* __restrict__ c0_all,
    float* sh){
  float* h_lds = sh; // [32][256]
  int tid = threadIdx.x;
  for (int i = tid; i < Bn*Un; i += 256) h_lds[i] = hprev[i];
  __syncthreads();
  int j0 = blk*16;
  #pragma unroll
  for (int it = 0; it < 2; ++it){
    int idx = tid + it*256;
    int b = idx >> 4, cc = idx & 15;
    int col = j0 + cc;
    const float* zr = Zx + (size_t)(step*Bn + b)*Z4n;
    float zi = zr[col], zf = zr[col+Un], zg = zr[col+2*Un], zo = zr[col+3*Un];
    const float* hb = h_lds + b*Un;
    const float* wcol = Wr + col;
    for (int u = 0; u < Un; ++u){
      float hv = hb[u];
      const float* wrow = wcol + (size_t)u*Z4n;
      zi += hv*wrow[0];
      zf += hv*wrow[Un];
      zg += hv*wrow[2*Un];
      zo += hv*wrow[3*Un];
    }
    float cold = c_state[b*Un + col];
    float cn = sigmoid_f(zf)*cold + sigmoid_f(zi)*tanhf(zg);
    float hn = sigmoid_f(zo)*tanhf(cn);
    c_state[b*Un + col] = cn;
    hout[b*Un + col] = hn;
    if (b == 0) c0_all[step*Un + col] = cn;
  }
}

// attention for batch-row b: scores -> softmax -> a, cov update, cov_loss
__device__ __forceinline__ void attn_dev(int t, int b,
    const float* __restrict__ dec_attn, const float* __restrict__ Wc,
    const float* __restrict__ Wa, const float* __restrict__ enc_attn,
    float* __restrict__ cov, float* __restrict__ a_all,
    float* __restrict__ covloss, float* sh){
  float* cov_l = sh;          // 400
  float* sc_l  = sh + 400;    // 400
  float* red   = sh + 800;    // 16
  int tid = threadIdx.x;
  int lane = tid & 63, wv = tid >> 6;
  float da[4], wc[4], wa[4];
  #pragma unroll
  for (int q = 0; q < 4; ++q){
    int k = q*64 + lane;
    da[q] = dec_attn[b*AUn + k];
    wc[q] = Wc[k];
    wa[q] = Wa[k];
  }
  for (int s = tid; s < Sn; s += 256) cov_l[s] = cov[b*Sn + s];
  __syncthreads();
  const float* encb = enc_attn + (size_t)b*Sn*AUn;
  for (int s = wv; s < Sn; s += 4){
    float cvv = cov_l[s];
    const float* e = encb + (size_t)s*AUn;
    float p = 0.f;
    #pragma unroll
    for (int q = 0; q < 4; ++q){
      float x = e[q*64 + lane] + cvv*wc[q] + da[q];
      p += tanh_fast(x) * wa[q];
    }
    #pragma unroll
    for (int m = 1; m < 64; m <<= 1) p += __shfl_xor(p, m);
    if (lane == 0) sc_l[s] = p;
  }
  __syncthreads();
  float part = 0.f;
  for (int s = tid; s < Sn; s += 256){
    float ev = __expf(sc_l[s]);   // |score| <= ~5: exp safe without max-sub
    sc_l[s] = ev;
    part += ev;
  }
  #pragma unroll
  for (int m = 1; m < 64; m <<= 1) part += __shfl_xor(part, m);
  if (lane == 0) red[wv] = part;
  __syncthreads();
  float inv = 1.f / (red[0]+red[1]+red[2]+red[3]);
  float clp = 0.f;
  for (int s = tid; s < Sn; s += 256){
    float av = sc_l[s] * inv;
    float co = cov_l[s];
    a_all[(size_t)(t*Bn + b)*Sn + s] = av;
    clp += fminf(co, av);
    cov[b*Sn + s] = co + av;
  }
  #pragma unroll
  for (int m = 1; m < 64; m <<= 1) clp += __shfl_xor(clp, m);
  if (lane == 0) red[8+wv] = clp;
  __syncthreads();
  if (tid == 0) covloss[b*Tn + t] = red[8]+red[9]+red[10]+red[11];
}

// dec_attn = [h;c] @ Wd + bd  (8 blocks x 32 cols)
__global__ __launch_bounds__(256) void k_dec(const float* __restrict__ h,
    const float* __restrict__ c_state, const float* __restrict__ Wd,
    const float* __restrict__ bd, float* __restrict__ dec_attn){
  __shared__ float st[Bn*2*Un];
  int tid = threadIdx.x;
  for (int i = tid; i < Bn*Un; i += 256){
    int b = i >> 8, u = i & 255;
    st[b*512 + u]       = h[i];
    st[b*512 + 256 + u] = c_state[i];
  }
  __syncthreads();
  int j0 = blockIdx.x * 32;
  #pragma unroll
  for (int it = 0; it < 4; ++it){
    int idx = tid + it*256;
    int b = idx >> 5, cc = idx & 31;
    int j = j0 + cc;
    float acc = bd[j];
    const float* sb = st + b*512;
    for (int u = 0; u < 512; ++u) acc += sb[u] * Wd[u*AUn + j];
    dec_attn[b*AUn + j] = acc;
  }
}

// fused per-step: blocks [0,32) = attention(t), blocks [32,48) = LSTM(t+1)
__global__ __launch_bounds__(256) void k_step(int t,
    const float* __restrict__ Zx, const float* __restrict__ Wr,
    float* __restrict__ h_all, float* __restrict__ c_state, float* __restrict__ c0_all,
    const float* __restrict__ dec_attn, const float* __restrict__ Wc,
    const float* __restrict__ Wa, const float* __restrict__ enc_attn,
    float* __restrict__ cov, float* __restrict__ a_all, float* __restrict__ covloss){
  __shared__ float sh[Bn*Un];
  int bid = blockIdx.x;
  if (bid < 32){
    attn_dev(t, bid, dec_attn, Wc, Wa, enc_attn, cov, a_all, covloss, sh);
  } else if (t + 1 < Tn){
    lstm_dev(t+1, bid-32, h_all + (size_t)t*Bn*Un, Zx, Wr,
             h_all + (size_t)(t+1)*Bn*Un, c_state, c0_all, sh);
  }
}

__global__ __launch_bounds__(256) void k_lstm0(const float* __restrict__ h0,
    const float* __restrict__ Zx, const float* __restrict__ Wr,
    float* __restrict__ h_all, float* __restrict__ c_state, float* __restrict__ c0_all){
  __shared__ float sh[Bn*Un];
  lstm_dev(0, blockIdx.x, h0, Zx, Wr, h_all, c_state, c0_all, sh);
}

// ---------------- post-loop kernels ----------------

// hid = h_all @ W1 + b1 -> bf16    (block per t)
__global__ __launch_bounds__(256) void k_hid(const float* __restrict__ h_all,
    const float* __restrict__ W1, const float* __restrict__ b1, ushort_t* __restrict__ hid){
  __shared__ float hl[Bn*Un];
  int t = blockIdx.x, tid = threadIdx.x;
  for (int i = tid; i < Bn*Un; i += 256) hl[i] = h_all[(size_t)t*Bn*Un + i];
  __syncthreads();
  int j = tid;
  float bj = b1[j];
  float acc[32];
  #pragma unroll
  for (int r = 0; r < 32; ++r) acc[r] = bj;
  for (int u = 0; u < Un; ++u){
    float wv = W1[u*Un + j];
    #pragma unroll
    for (int r = 0; r < 32; ++r) acc[r] += hl[r*Un + u]*wv;
  }
  #pragma unroll
  for (int r = 0; r < 32; ++r) hid[(size_t)(t*Bn + r)*Un + j] = f2bf(acc[r]);
}

// pg[t] via row-0 quirk: c_vec0 then g then sigmoid(g@Wg)
__global__ __launch_bounds__(256) void k_pg(const float* __restrict__ a_all,
    const float* __restrict__ enc_out, const float* __restrict__ h_all,
    const float* __restrict__ c0_all, const float* __restrict__ gpWs,
    const float* __restrict__ gpWc, const float* __restrict__ gpx,
    const float* __restrict__ gpWg, float* __restrict__ pg){
  __shared__ float al[Sn];
  __shared__ float cv[ENCn];
  __shared__ float red[4];
  int t = blockIdx.x, tid = threadIdx.x;
  for (int s = tid; s < Sn; s += 256) al[s] = a_all[(size_t)(t*Bn + 0)*Sn + s];
  __syncthreads();
  for (int e = tid; e < ENCn; e += 256){
    float acc = 0.f;
    for (int s = 0; s < Sn; ++s) acc += enc_out[(size_t)s*ENCn + e]*al[s];
    cv[e] = acc;
  }
  __syncthreads();
  int j = tid;
  float g = gpx[t*GPn + j];
  const float* h0r = h_all + (size_t)t*Bn*Un;       // b = 0 row
  const float* c0r = c0_all + t*Un;
  for (int u = 0; u < Un; ++u) g += h0r[u]*gpWs[u*GPn + j];
  for (int u = 0; u < Un; ++u) g += c0r[u]*gpWs[(Un+u)*GPn + j];
  for (int e = 0; e < ENCn; ++e) g += cv[e]*gpWc[e*GPn + j];
  float v = g * gpWg[j];
  int lane = tid & 63, wv2 = tid >> 6;
  #pragma unroll
  for (int m = 1; m < 64; m <<= 1) v += __shfl_xor(v, m);
  if (lane == 0) red[wv2] = v;
  __syncthreads();
  if (tid == 0) pg[t] = 1.f/(1.f+__expf(-(red[0]+red[1]+red[2]+red[3])));
}

// mode 0: Ssum[r] += sum_v exp(logit);  mode 1: probs = pg*exp/S (+OOV zeros) + amax
__global__ __launch_bounds__(256) void k_gemm(const ushort_t* __restrict__ A,
    const ushort_t* __restrict__ Bw, const float* __restrict__ b2,
    float* __restrict__ Ssum, u64* __restrict__ amax, const float* __restrict__ pg,
    float* __restrict__ probs, int mode){
  int r0 = blockIdx.x * 64;
  int n0 = blockIdx.y * 256;
  int tid = threadIdx.x;
  if (mode == 1 && n0 >= Vn){
    for (int idx = tid; idx < 64*OOVn; idx += 256){
      int i = idx/OOVn, vv = idx%OOVn;
      int r = r0+i; int tt = r>>5, bb = r&31;
      probs[(size_t)(bb*Tn+tt)*VEn + Vn + vv] = 0.f;
    }
    return;
  }
  __shared__ ushort_t Al[64*264];    // [64][256] pad 8
  __shared__ ushort_t Bt[256*40];    // transposed [n=256][k=32] pad 8
  {
    int row = tid>>2, kb = (tid&3)*64;
    const ushort_t* ga = A + (size_t)(r0+row)*256 + kb;
    ushort_t* la = Al + row*264 + kb;
    #pragma unroll
    for (int j = 0; j < 8; ++j)
      *((uint4*)la + j) = *((const uint4*)ga + j);
  }
  f32x4 acc[16];
  #pragma unroll
  for (int i = 0; i < 16; ++i) acc[i] = (f32x4){0.f,0.f,0.f,0.f};
  int lane = tid & 63, w = tid >> 6;
  for (int kk = 0; kk < 8; ++kk){
    __syncthreads();   // protect Bt from previous iter readers
    {
      int k = tid>>3, nb = (tid&7)*32;
      const ushort_t* gb = Bw + (size_t)(kk*32+k)*Vn + n0 + nb;
      #pragma unroll
      for (int u = 0; u < 4; ++u){
        uint4 d = *(const uint4*)(gb + u*8);
        const ushort_t* e = (const ushort_t*)&d;
        #pragma unroll
        for (int j = 0; j < 8; ++j) Bt[(nb+u*8+j)*40 + k] = e[j];
      }
    }
    __syncthreads();
    bf16x8 af = *(const bf16x8*)(Al + (w*16 + (lane&15))*264 + kk*32 + (lane>>4)*8);
    #pragma unroll
    for (int nt = 0; nt < 16; ++nt){
      bf16x8 bf = *(const bf16x8*)(Bt + (nt*16 + (lane&15))*40 + (lane>>4)*8);
      acc[nt] = __builtin_amdgcn_mfma_f32_16x16x32_bf16(af, bf, acc[nt], 0, 0, 0);
    }
  }
  int colbase = n0 + (lane&15);
  int rowloc = w*16 + (lane>>4)*4;
  if (mode == 0){
    float rs[4] = {0.f,0.f,0.f,0.f};
    #pragma unroll
    for (int nt = 0; nt < 16; ++nt){
      int v = colbase + nt*16;
      float bb = b2[v];
      #pragma unroll
      for (int i = 0; i < 4; ++i) rs[i] += __expf(acc[nt][i] + bb);
    }
    #pragma unroll
    for (int m = 1; m < 16; m <<= 1)
      #pragma unroll
      for (int i = 0; i < 4; ++i) rs[i] += __shfl_xor(rs[i], m);
    if ((lane&15) == 0)
      #pragma unroll
      for (int i = 0; i < 4; ++i) atomicAdd(&Ssum[r0+rowloc+i], rs[i]);
  } else {
    float sc[4]; size_t obase[4];
    #pragma unroll
    for (int i = 0; i < 4; ++i){
      int r = r0+rowloc+i; int tt = r>>5, bb = r&31;
      sc[i] = pg[tt] / Ssum[r];
      obase[i] = (size_t)(bb*Tn+tt)*VEn;
    }
    u64 pm[4] = {0,0,0,0};
    #pragma unroll
    for (int nt = 0; nt < 16; ++nt){
      int v = colbase + nt*16;
      float bb = b2[v];
      #pragma unroll
      for (int i = 0; i < 4; ++i){
        float val = __expf(acc[nt][i] + bb) * sc[i];
        probs[obase[i] + v] = val;
        u64 p = ((u64)__float_as_uint(val)<<32) | (u64)(0xFFFFFFFFu - (unsigned)v);
        pm[i] = p > pm[i] ? p : pm[i];
      }
    }
    #pragma unroll
    for (int m = 1; m < 16; m <<= 1)
      #pragma unroll
      for (int i = 0; i < 4; ++i){
        u64 o = shfl_xor_u64(pm[i], m);
        pm[i] = o > pm[i] ? o : pm[i];
      }
    if ((lane&15) == 0)
      #pragma unroll
      for (int i = 0; i < 4; ++i) atomicMax(&amax[r0+rowloc+i], pm[i]);
  }
}

// scatter copy-dist into probs (deduped single-writer) + update amax
__global__ __launch_bounds__(256) void k_scatter(const int* __restrict__ ext,
    const float* __restrict__ a_all, const float* __restrict__ pg,
    float* __restrict__ probs, u64* __restrict__ amax){
  __shared__ int tok[Sn];
  __shared__ float val[Sn];
  int r = blockIdx.x; int t = r>>5, b = r&31;
  float c1 = 1.f - pg[t];
  int tid = threadIdx.x;
  for (int s = tid; s < Sn; s += 256){
    tok[s] = ext[b*Sn + s];
    val[s] = c1 * a_all[(size_t)r*Sn + s];
  }
  __syncthreads();
  size_t obase = (size_t)(b*Tn + t)*VEn;
  for (int s = tid; s < Sn; s += 256){
    int tk = tok[s];
    bool leader = true;
    float tot = 0.f;
    for (int s2 = 0; s2 < Sn; ++s2){
      if (tok[s2] == tk){
        if (s2 < s){ leader = false; break; }
        tot += val[s2];
      }
    }
    if (leader){
      float nv = probs[obase + tk] + tot;
      probs[obase + tk] = nv;
      u64 p = ((u64)__float_as_uint(nv)<<32) | (u64)(0xFFFFFFFFu - (unsigned)tk);
      atomicMax(&amax[r], p);
    }
  }
}

__global__ __launch_bounds__(256) void k_seqout(const u64* __restrict__ amax,
    float* __restrict__ seqs){
  int r = blockIdx.x*256 + threadIdx.x;
  if (r >= Tn*Bn) return;
  int t = r>>5, b = r&31;
  unsigned tk = 0xFFFFFFFFu - (unsigned)(amax[r] & 0xFFFFFFFFull);
  seqs[b*Tn + t] = (float)tk;
}

// ---------------- host launch ----------------

extern "C" void kernel_launch(void* const* d_in, const int* in_sizes, int n_in,
                              void* d_out, int out_size, void* d_ws, size_t ws_size,
                              hipStream_t stream){
  (void)in_sizes; (void)n_in; (void)out_size; (void)ws_size;
  const int*   gt       = (const int*)d_in[0];
  const int*   ext      = (const int*)d_in[1];
  const float* enc_out  = (const float*)d_in[2];
  const float* enc_attn = (const float*)d_in[3];
  const float* h0       = (const float*)d_in[4];
  const float* c0       = (const float*)d_in[5];
  const float* emb      = (const float*)d_in[6];
  const float* Wk       = (const float*)d_in[7];
  const float* Wr       = (const float*)d_in[8];
  const float* lb       = (const float*)d_in[9];
  const float* Wd       = (const float*)d_in[10];
  const float* bd       = (const float*)d_in[11];
  const float* Wc       = (const float*)d_in[12];
  const float* Wa       = (const float*)d_in[13];
  const float* W1       = (const float*)d_in[14];
  const float* b1       = (const float*)d_in[15];
  const float* W2       = (const float*)d_in[16];
  const float* b2       = (const float*)d_in[17];
  const float* gpWs     = (const float*)d_in[18];
  const float* gpWc     = (const float*)d_in[19];
  const float* gpWi     = (const float*)d_in[20];
  const float* gpbi     = (const float*)d_in[21];
  const float* gpWg     = (const float*)d_in[22];

  float* probs   = (float*)d_out;
  float* seqs    = probs + (size_t)Bn*Tn*VEn;
  float* covloss = seqs + Bn*Tn;

  char* wp = (char*)d_ws;
  auto carve = [&](size_t bytes)->void*{
    void* p = (void*)wp; wp += (bytes + 255) & ~(size_t)255; return p;
  };
  float*    Xall    = (float*)carve((size_t)3200*En*4);
  float*    Zx      = (float*)carve((size_t)3200*Z4n*4);
  float*    gpx     = (float*)carve((size_t)Tn*GPn*4);
  float*    h_all   = (float*)carve((size_t)Tn*Bn*Un*4);
  float*    c_state = (float*)carve((size_t)Bn*Un*4);
  float*    c0_all  = (float*)carve((size_t)Tn*Un*4);
  float*    cov     = (float*)carve((size_t)Bn*Sn*4);
  float*    dec_at  = (float*)carve((size_t)Bn*AUn*4);
  float*    a_all   = (float*)carve((size_t)3200*Sn*4);
  ushort_t* hid_bf  = (ushort_t*)carve((size_t)3200*Un*2);
  ushort_t* W2bf    = (ushort_t*)carve((size_t)Un*Vn*2);
  float*    Ssum    = (float*)carve((size_t)3200*4);
  u64*      amax    = (u64*)carve((size_t)3200*8);
  float*    pg      = (float*)carve((size_t)Tn*4);

  hipMemsetAsync(Ssum, 0, 3200*4, stream);
  hipMemsetAsync(amax, 0, 3200*8, stream);

  k_init  <<<50, 256, 0, stream>>>(c0, c_state, cov);
  k_gather<<<3200, 256, 0, stream>>>(gt, emb, Xall);
  k_zx    <<<dim3(50,16), 256, 0, stream>>>(Xall, Wk, lb, Zx);
  k_gpx   <<<Tn, 256, 0, stream>>>(Xall, gpWi, gpbi, gpx);
  k_w2bf  <<<4000, 256, 0, stream>>>(W2, W2bf);

  k_lstm0 <<<16, 256, 0, stream>>>(h0, Zx, Wr, h_all, c_state, c0_all);
  k_dec   <<<8, 256, 0, stream>>>(h_all, c_state, Wd, bd, dec_at);
  for (int t = 0; t < Tn; ++t){
    k_step<<<48, 256, 0, stream>>>(t, Zx, Wr, h_all, c_state, c0_all,
                                   dec_at, Wc, Wa, enc_attn, cov, a_all, covloss);
    if (t + 1 < Tn)
      k_dec<<<8, 256, 0, stream>>>(h_all + (size_t)(t+1)*Bn*Un, c_state, Wd, bd, dec_at);
  }

  k_hid <<<Tn, 256, 0, stream>>>(h_all, W1, b1, hid_bf);
  k_pg  <<<Tn, 256, 0, stream>>>(a_all, enc_out, h_all, c0_all, gpWs, gpWc, gpx, gpWg, pg);
  k_gemm<<<dim3(50,125), 256, 0, stream>>>(hid_bf, W2bf, b2, Ssum, amax, pg, probs, 0);
  k_gemm<<<dim3(50,126), 256, 0, stream>>>(hid_bf, W2bf, b2, Ssum, amax, pg, probs, 1);
  k_scatter<<<3200, 256, 0, stream>>>(ext, a_all, pg, probs, amax);
  k_seqout <<<13, 256, 0, stream>>>(amax, seqs);
}

// Round 2
// 3416.514 us; speedup vs baseline: 3.1480x; 3.1480x over previous
//
#include <hip/hip_runtime.h>
#include <hip/hip_bf16.h>

#define Bn 32
#define Sn 400
#define Tn 100
#define Vn 32000
#define OOVn 100
#define VEn 32100
#define En 512
#define Un 256
#define AUn 256
#define GPn 256
#define ENCn 512
#define Z4n 1024

typedef __attribute__((ext_vector_type(8))) short bf16x8;
typedef __attribute__((ext_vector_type(4))) float f32x4;
typedef unsigned short ushort_t;
typedef unsigned long long u64;

__device__ __forceinline__ float rcp_f(float x){ return __builtin_amdgcn_rcpf(x); }
__device__ __forceinline__ float tanh_fast(float x){
  float e2 = __expf(2.f*x);
  return 1.f - 2.f*rcp_f(e2 + 1.f);
}
__device__ __forceinline__ float sigmoid_f(float x){ return 1.f/(1.f+__expf(-x)); }
__device__ __forceinline__ ushort_t f2bf(float f){
  unsigned u = __float_as_uint(f);
  unsigned r = (u + 0x7FFFu + ((u>>16)&1u)) >> 16;   // RNE
  return (ushort_t)r;
}
__device__ __forceinline__ u64 shfl_xor_u64(u64 v, int m){
  unsigned lo = (unsigned)v, hi = (unsigned)(v>>32);
  lo = (unsigned)__shfl_xor((int)lo, m);
  hi = (unsigned)__shfl_xor((int)hi, m);
  return ((u64)hi<<32)|(u64)lo;
}

// ---------------- pre-loop kernels ----------------

__global__ __launch_bounds__(256) void k_gather(const int* __restrict__ gt,
    const float* __restrict__ emb, float* __restrict__ Xall){
  int r = blockIdx.x;                 // r = t*32 + b
  int t = r >> 5, b = r & 31;
  int tok = gt[b*Tn + t];
  const float* src = emb + (size_t)tok*En;
  float* dst = Xall + (size_t)r*En;
  for (int i = threadIdx.x; i < En; i += 256) dst[i] = src[i];
}

// Zx = Xall @ Wk + bias   [3200,512]@[512,1024], f32 tiled 64x64
__global__ __launch_bounds__(256) void k_zx(const float* __restrict__ X,
    const float* __restrict__ Wk, const float* __restrict__ bias, float* __restrict__ Zx){
  __shared__ float As[64][17];
  __shared__ float Bs[16][65];
  int r0 = blockIdx.x * 64;
  int c0 = blockIdx.y * 64;
  int tid = threadIdx.x;
  int ty = tid >> 4, tx = tid & 15;
  float acc[4][4] = {};
  for (int k0 = 0; k0 < En; k0 += 16){
    #pragma unroll
    for (int p = 0; p < 4; ++p){
      int row = (tid>>4) + p*16, kk = tid & 15;
      As[row][kk] = X[(size_t)(r0+row)*En + k0 + kk];
    }
    #pragma unroll
    for (int p = 0; p < 4; ++p){
      int kk = (tid>>6) + p*4, cc = tid & 63;
      Bs[kk][cc] = Wk[(size_t)(k0+kk)*Z4n + c0 + cc];
    }
    __syncthreads();
    #pragma unroll
    for (int kk = 0; kk < 16; ++kk){
      float av[4], bv[4];
      #pragma unroll
      for (int i=0;i<4;++i) av[i] = As[ty*4+i][kk];
      #pragma unroll
      for (int j=0;j<4;++j) bv[j] = Bs[kk][tx*4+j];
      #pragma unroll
      for (int i=0;i<4;++i)
        #pragma unroll
        for (int j=0;j<4;++j) acc[i][j] += av[i]*bv[j];
    }
    __syncthreads();
  }
  #pragma unroll
  for (int i=0;i<4;++i){
    int row = r0 + ty*4 + i;
    #pragma unroll
    for (int j=0;j<4;++j){
      int col = c0 + tx*4 + j;
      Zx[(size_t)row*Z4n + col] = acc[i][j] + bias[col];
    }
  }
}

// gpx[t,:] = x[t,b=0,:] @ gp_Wi + gp_bi
__global__ __launch_bounds__(256) void k_gpx(const float* __restrict__ Xall,
    const float* __restrict__ Wi, const float* __restrict__ bi, float* __restrict__ gpx){
  int t = blockIdx.x, j = threadIdx.x;
  const float* x = Xall + (size_t)(t*Bn + 0)*En;
  float acc = bi[j];
  for (int u = 0; u < En; ++u) acc += x[u]*Wi[u*GPn + j];
  gpx[t*GPn + j] = acc;
}

// W2 [256][32000] f32 -> W2T [32000][256] bf16 (LDS-tiled transpose)
__global__ __launch_bounds__(256) void k_w2t(const float* __restrict__ W2,
    ushort_t* __restrict__ W2T){
  __shared__ float tile[64][65];
  int n0 = blockIdx.x * 64;   // 500
  int k0 = blockIdx.y * 64;   // 4
  int tx = threadIdx.x & 63, ty4 = threadIdx.x >> 6;
  #pragma unroll
  for (int i = 0; i < 16; ++i){
    int k = ty4 + i*4;
    tile[k][tx] = W2[(size_t)(k0+k)*Vn + n0 + tx];
  }
  __syncthreads();
  #pragma unroll
  for (int i = 0; i < 16; ++i){
    int n = ty4 + i*4;
    W2T[(size_t)(n0+n)*Un + k0 + tx] = f2bf(tile[tx][n]);
  }
}

// ---------------- persistent per-batch-row recurrent kernel ----------------
// 32 blocks (one per b) x 1024 threads. h, c, cov live in LDS across all T steps.

__global__ __launch_bounds__(1024) void k_loop(
    const float* __restrict__ Zx, const float* __restrict__ Wr,
    const float* __restrict__ Wd, const float* __restrict__ bd,
    const float* __restrict__ Wc, const float* __restrict__ Wa,
    const float* __restrict__ enc_attn,
    const float* __restrict__ h0, const float* __restrict__ c0,
    float* __restrict__ h_all, float* __restrict__ c0_all,
    float* __restrict__ a_all, float* __restrict__ covloss){
  __shared__ float h_lds[Un], c_lds[Un], z_lds[Z4n], dec_lds[AUn];
  __shared__ float decp[4][AUn];
  __shared__ float cov_lds[Sn], sc_lds[Sn];
  __shared__ float red[20];
  int b = blockIdx.x;
  int tid = threadIdx.x;
  int lane = tid & 63, w = tid >> 6;

  if (tid < Un){ h_lds[tid] = h0[b*Un+tid]; c_lds[tid] = c0[b*Un+tid]; }
  if (tid < Sn) cov_lds[tid] = 0.f;
  float wcq[4], waq[4];
  #pragma unroll
  for (int q = 0; q < 4; ++q){ wcq[q] = Wc[q*64+lane]; waq[q] = Wa[q*64+lane]; }
  const float* encb = enc_attn + (size_t)b*Sn*AUn;
  __syncthreads();

  for (int t = 0; t < Tn; ++t){
    // ---- phase 1: z[j] = Zx[t,b,j] + sum_u h[u]*Wr[u][j]  (j = tid) ----
    {
      float acc = Zx[(size_t)(t*Bn+b)*Z4n + tid];
      const float* wr = Wr + tid;
      #pragma unroll 4
      for (int u = 0; u < Un; ++u){
        acc += h_lds[u] * wr[0];
        wr += Z4n;
      }
      z_lds[tid] = acc;
    }
    __syncthreads();
    // ---- phase 2: gates ----
    if (tid < Un){
      float zi = z_lds[tid], zf = z_lds[tid+Un], zg = z_lds[tid+2*Un], zo = z_lds[tid+3*Un];
      float cn = sigmoid_f(zf)*c_lds[tid] + sigmoid_f(zi)*tanhf(zg);
      float hn = sigmoid_f(zo)*tanhf(cn);
      c_lds[tid] = cn; h_lds[tid] = hn;
      h_all[(size_t)(t*Bn+b)*Un + tid] = hn;
      if (b == 0) c0_all[t*Un + tid] = cn;
    }
    __syncthreads();
    // ---- phase 3: dec_attn = [h;c] @ Wd + bd (split-k x4 in-block) ----
    {
      int j = tid & 255, part = tid >> 8;
      const float* src = (part < 2) ? (h_lds + part*128) : (c_lds + (part-2)*128);
      const float* wd = Wd + (size_t)(part*128)*AUn + j;
      float acc = 0.f;
      #pragma unroll 4
      for (int uu = 0; uu < 128; ++uu){
        acc += src[uu] * wd[0];
        wd += AUn;
      }
      decp[part][j] = acc;
    }
    __syncthreads();
    if (tid < AUn)
      dec_lds[tid] = decp[0][tid]+decp[1][tid]+decp[2][tid]+decp[3][tid] + bd[tid];
    __syncthreads();
    // ---- phase 4: scores (wave w handles s = w, w+16, ...) ----
    {
      float da[4];
      #pragma unroll
      for (int q = 0; q < 4; ++q) da[q] = dec_lds[q*64+lane];
      for (int s = w; s < Sn; s += 16){
        float cvv = cov_lds[s];
        const float* e = encb + (size_t)s*AUn;
        float p = 0.f;
        #pragma unroll
        for (int q = 0; q < 4; ++q){
          float x = e[q*64+lane] + cvv*wcq[q] + da[q];
          p += tanh_fast(x)*waq[q];
        }
        #pragma unroll
        for (int m = 1; m < 64; m <<= 1) p += __shfl_xor(p, m);
        if (lane == 0) sc_lds[s] = p;
      }
    }
    __syncthreads();
    // ---- phase 5: softmax + cov update + a_all + covloss ----
    {
      float ev = 0.f;
      if (tid < Sn) ev = __expf(sc_lds[tid]);
      float p = ev;
      #pragma unroll
      for (int m = 1; m < 64; m <<= 1) p += __shfl_xor(p, m);
      if (lane == 0) red[w] = p;
      __syncthreads();
      if (tid == 0){
        float tot = 0.f;
        #pragma unroll
        for (int i = 0; i < 16; ++i) tot += red[i];
        red[16] = 1.f / tot;
      }
      __syncthreads();
      float inv = red[16];
      float clp = 0.f;
      if (tid < Sn){
        float a = ev * inv;
        float co = cov_lds[tid];
        a_all[(size_t)(t*Bn+b)*Sn + tid] = a;
        clp = fminf(co, a);
        cov_lds[tid] = co + a;
      }
      #pragma unroll
      for (int m = 1; m < 64; m <<= 1) clp += __shfl_xor(clp, m);
      if (lane == 0) red[w] = clp;
      __syncthreads();
      if (tid == 0){
        float cl = 0.f;
        #pragma unroll
        for (int i = 0; i < 16; ++i) cl += red[i];
        covloss[b*Tn + t] = cl;
      }
      __syncthreads();
    }
  }
}

// ---------------- post-loop kernels ----------------

// hid = h_all @ W1 + b1 -> bf16    (block per t)
__global__ __launch_bounds__(256) void k_hid(const float* __restrict__ h_all,
    const float* __restrict__ W1, const float* __restrict__ b1, ushort_t* __restrict__ hid){
  __shared__ float hl[Bn*Un];
  int t = blockIdx.x, tid = threadIdx.x;
  for (int i = tid; i < Bn*Un; i += 256) hl[i] = h_all[(size_t)t*Bn*Un + i];
  __syncthreads();
  int j = tid;
  float bj = b1[j];
  float acc[32];
  #pragma unroll
  for (int r = 0; r < 32; ++r) acc[r] = bj;
  for (int u = 0; u < Un; ++u){
    float wv = W1[u*Un + j];
    #pragma unroll
    for (int r = 0; r < 32; ++r) acc[r] += hl[r*Un + u]*wv;
  }
  #pragma unroll
  for (int r = 0; r < 32; ++r) hid[(size_t)(t*Bn + r)*Un + j] = f2bf(acc[r]);
}

// pg[t] via row-0 quirk
__global__ __launch_bounds__(256) void k_pg(const float* __restrict__ a_all,
    const float* __restrict__ enc_out, const float* __restrict__ h_all,
    const float* __restrict__ c0_all, const float* __restrict__ gpWs,
    const float* __restrict__ gpWc, const float* __restrict__ gpx,
    const float* __restrict__ gpWg, float* __restrict__ pg){
  __shared__ float al[Sn];
  __shared__ float cv[ENCn];
  __shared__ float red[4];
  int t = blockIdx.x, tid = threadIdx.x;
  for (int s = tid; s < Sn; s += 256) al[s] = a_all[(size_t)(t*Bn + 0)*Sn + s];
  __syncthreads();
  for (int e = tid; e < ENCn; e += 256){
    float acc = 0.f;
    for (int s = 0; s < Sn; ++s) acc += enc_out[(size_t)s*ENCn + e]*al[s];
    cv[e] = acc;
  }
  __syncthreads();
  int j = tid;
  float g = gpx[t*GPn + j];
  const float* h0r = h_all + (size_t)t*Bn*Un;       // b = 0 row
  const float* c0r = c0_all + t*Un;
  for (int u = 0; u < Un; ++u) g += h0r[u]*gpWs[u*GPn + j];
  for (int u = 0; u < Un; ++u) g += c0r[u]*gpWs[(Un+u)*GPn + j];
  for (int e = 0; e < ENCn; ++e) g += cv[e]*gpWc[e*GPn + j];
  float v = g * gpWg[j];
  int lane = tid & 63, wv2 = tid >> 6;
  #pragma unroll
  for (int m = 1; m < 64; m <<= 1) v += __shfl_xor(v, m);
  if (lane == 0) red[wv2] = v;
  __syncthreads();
  if (tid == 0) pg[t] = 1.f/(1.f+__expf(-(red[0]+red[1]+red[2]+red[3])));
}

// GEMM: A = hid [3200][256] bf16, B = W2T [32000][256] bf16.
// mode 0: Ssum[r] += sum_v exp(logit);  mode 1: probs = pg*exp/S (+OOV zeros) + amax
__global__ __launch_bounds__(256) void k_gemm(const ushort_t* __restrict__ A,
    const ushort_t* __restrict__ Bw, const float* __restrict__ b2,
    float* __restrict__ Ssum, u64* __restrict__ amax, const float* __restrict__ pg,
    float* __restrict__ probs, int mode){
  int r0 = blockIdx.x * 64;
  int n0 = blockIdx.y * 256;
  int tid = threadIdx.x;
  if (mode == 1 && n0 >= Vn){
    for (int idx = tid; idx < 64*OOVn; idx += 256){
      int i = idx/OOVn, vv = idx%OOVn;
      int r = r0+i; int tt = r>>5, bb = r&31;
      probs[(size_t)(bb*Tn+tt)*VEn + Vn + vv] = 0.f;
    }
    return;
  }
  __shared__ ushort_t Bs[64*264];          // [64 n][256 k + pad8]
  int lane = tid & 63, w = tid >> 6;
  // A-fragments in registers (wave w owns m-tile w: rows r0+w*16 .. +15)
  bf16x8 af[8];
  {
    const ushort_t* ar = A + (size_t)(r0 + w*16 + (lane&15))*Un + (lane>>4)*8;
    #pragma unroll
    for (int kk = 0; kk < 8; ++kk) af[kk] = *(const bf16x8*)(ar + kk*32);
  }
  f32x4 acc[16];
  #pragma unroll
  for (int i = 0; i < 16; ++i) acc[i] = (f32x4){0.f,0.f,0.f,0.f};

  for (int nsub = 0; nsub < 4; ++nsub){
    __syncthreads();
    {
      const ushort_t* gb = Bw + (size_t)(n0 + nsub*64)*Un;
      #pragma unroll
      for (int i = 0; i < 8; ++i){
        int chunk = tid + i*256;           // 2048 x 16B chunks
        int rr = chunk >> 5, cc = chunk & 31;
        uint4 d = *(const uint4*)(gb + rr*Un + cc*8);
        *(uint4*)(Bs + rr*264 + cc*8) = d;
      }
    }
    __syncthreads();
    #pragma unroll
    for (int kk = 0; kk < 8; ++kk){
      #pragma unroll
      for (int ntl = 0; ntl < 4; ++ntl){
        bf16x8 bf = *(const bf16x8*)(Bs + (ntl*16 + (lane&15))*264 + kk*32 + (lane>>4)*8);
        acc[nsub*4+ntl] = __builtin_amdgcn_mfma_f32_16x16x32_bf16(af[kk], bf, acc[nsub*4+ntl], 0, 0, 0);
      }
    }
  }

  int rowloc = w*16 + (lane>>4)*4;
  if (mode == 0){
    float rs[4] = {0.f,0.f,0.f,0.f};
    #pragma unroll
    for (int nt = 0; nt < 16; ++nt){
      int v = n0 + (nt>>2)*64 + (nt&3)*16 + (lane&15);
      float bb = b2[v];
      #pragma unroll
      for (int i = 0; i < 4; ++i) rs[i] += __expf(acc[nt][i] + bb);
    }
    #pragma unroll
    for (int m = 1; m < 16; m <<= 1)
      #pragma unroll
      for (int i = 0; i < 4; ++i) rs[i] += __shfl_xor(rs[i], m);
    if ((lane&15) == 0)
      #pragma unroll
      for (int i = 0; i < 4; ++i) atomicAdd(&Ssum[r0+rowloc+i], rs[i]);
  } else {
    float sc[4]; size_t obase[4];
    #pragma unroll
    for (int i = 0; i < 4; ++i){
      int r = r0+rowloc+i; int tt = r>>5, bb = r&31;
      sc[i] = pg[tt] / Ssum[r];
      obase[i] = (size_t)(bb*Tn+tt)*VEn;
    }
    u64 pm[4] = {0,0,0,0};
    #pragma unroll
    for (int nt = 0; nt < 16; ++nt){
      int v = n0 + (nt>>2)*64 + (nt&3)*16 + (lane&15);
      float bb = b2[v];
      #pragma unroll
      for (int i = 0; i < 4; ++i){
        float val = __expf(acc[nt][i] + bb) * sc[i];
        probs[obase[i] + v] = val;
        u64 p = ((u64)__float_as_uint(val)<<32) | (u64)(0xFFFFFFFFu - (unsigned)v);
        pm[i] = p > pm[i] ? p : pm[i];
      }
    }
    #pragma unroll
    for (int m = 1; m < 16; m <<= 1)
      #pragma unroll
      for (int i = 0; i < 4; ++i){
        u64 o = shfl_xor_u64(pm[i], m);
        pm[i] = o > pm[i] ? o : pm[i];
      }
    if ((lane&15) == 0)
      #pragma unroll
      for (int i = 0; i < 4; ++i) atomicMax(&amax[r0+rowloc+i], pm[i]);
  }
}

// scatter copy-dist into probs (deduped single-writer) + update amax
__global__ __launch_bounds__(256) void k_scatter(const int* __restrict__ ext,
    const float* __restrict__ a_all, const float* __restrict__ pg,
    float* __restrict__ probs, u64* __restrict__ amax){
  __shared__ int tok[Sn];
  __shared__ float val[Sn];
  int r = blockIdx.x; int t = r>>5, b = r&31;
  float c1 = 1.f - pg[t];
  int tid = threadIdx.x;
  for (int s = tid; s < Sn; s += 256){
    tok[s] = ext[b*Sn + s];
    val[s] = c1 * a_all[(size_t)r*Sn + s];
  }
  __syncthreads();
  size_t obase = (size_t)(b*Tn + t)*VEn;
  for (int s = tid; s < Sn; s += 256){
    int tk = tok[s];
    bool leader = true;
    float tot = 0.f;
    for (int s2 = 0; s2 < Sn; ++s2){
      if (tok[s2] == tk){
        if (s2 < s){ leader = false; break; }
        tot += val[s2];
      }
    }
    if (leader){
      float nv = probs[obase + tk] + tot;
      probs[obase + tk] = nv;
      u64 p = ((u64)__float_as_uint(nv)<<32) | (u64)(0xFFFFFFFFu - (unsigned)tk);
      atomicMax(&amax[r], p);
    }
  }
}

__global__ __launch_bounds__(256) void k_seqout(const u64* __restrict__ amax,
    float* __restrict__ seqs){
  int r = blockIdx.x*256 + threadIdx.x;
  if (r >= Tn*Bn) return;
  int t = r>>5, b = r&31;
  unsigned tk = 0xFFFFFFFFu - (unsigned)(amax[r] & 0xFFFFFFFFull);
  seqs[b*Tn + t] = (float)tk;
}

// ---------------- host launch ----------------

extern "C" void kernel_launch(void* const* d_in, const int* in_sizes, int n_in,
                              void* d_out, int out_size, void* d_ws, size_t ws_size,
                              hipStream_t stream){
  (void)in_sizes; (void)n_in; (void)out_size; (void)ws_size;
  const int*   gt       = (const int*)d_in[0];
  const int*   ext      = (const int*)d_in[1];
  const float* enc_out  = (const float*)d_in[2];
  const float* enc_attn = (const float*)d_in[3];
  const float* h0       = (const float*)d_in[4];
  const float* c0       = (const float*)d_in[5];
  const float* emb      = (const float*)d_in[6];
  const float* Wk       = (const float*)d_in[7];
  const float* Wr       = (const float*)d_in[8];
  const float* lb       = (const float*)d_in[9];
  const float* Wd       = (const float*)d_in[10];
  const float* bd       = (const float*)d_in[11];
  const float* Wc       = (const float*)d_in[12];
  const float* Wa       = (const float*)d_in[13];
  const float* W1       = (const float*)d_in[14];
  const float* b1       = (const float*)d_in[15];
  const float* W2       = (const float*)d_in[16];
  const float* b2       = (const float*)d_in[17];
  const float* gpWs     = (const float*)d_in[18];
  const float* gpWc     = (const float*)d_in[19];
  const float* gpWi     = (const float*)d_in[20];
  const float* gpbi     = (const float*)d_in[21];
  const float* gpWg     = (const float*)d_in[22];

  float* probs   = (float*)d_out;
  float* seqs    = probs + (size_t)Bn*Tn*VEn;
  float* covloss = seqs + Bn*Tn;

  char* wp = (char*)d_ws;
  auto carve = [&](size_t bytes)->void*{
    void* p = (void*)wp; wp += (bytes + 255) & ~(size_t)255; return p;
  };
  float*    Xall    = (float*)carve((size_t)3200*En*4);
  float*    Zx      = (float*)carve((size_t)3200*Z4n*4);
  float*    gpx     = (float*)carve((size_t)Tn*GPn*4);
  float*    h_all   = (float*)carve((size_t)Tn*Bn*Un*4);
  float*    c0_all  = (float*)carve((size_t)Tn*Un*4);
  float*    a_all   = (float*)carve((size_t)3200*Sn*4);
  ushort_t* hid_bf  = (ushort_t*)carve((size_t)3200*Un*2);
  ushort_t* W2T     = (ushort_t*)carve((size_t)Vn*Un*2);
  float*    Ssum    = (float*)carve((size_t)3200*4);
  u64*      amax    = (u64*)carve((size_t)3200*8);
  float*    pg      = (float*)carve((size_t)Tn*4);

  hipMemsetAsync(Ssum, 0, 3200*4, stream);
  hipMemsetAsync(amax, 0, 3200*8, stream);

  k_gather<<<3200, 256, 0, stream>>>(gt, emb, Xall);
  k_zx    <<<dim3(50,16), 256, 0, stream>>>(Xall, Wk, lb, Zx);
  k_gpx   <<<Tn, 256, 0, stream>>>(Xall, gpWi, gpbi, gpx);
  k_w2t   <<<dim3(500,4), 256, 0, stream>>>(W2, W2T);

  k_loop  <<<Bn, 1024, 0, stream>>>(Zx, Wr, Wd, bd, Wc, Wa, enc_attn,
                                    h0, c0, h_all, c0_all, a_all, covloss);

  k_hid <<<Tn, 256, 0, stream>>>(h_all, W1, b1, hid_bf);
  k_pg  <<<Tn, 256, 0, stream>>>(a_all, enc_out, h_all, c0_all, gpWs, gpWc, gpx, gpWg, pg);
  k_gemm<<<dim3(50,125), 256, 0, stream>>>(hid_bf, W2T, b2, Ssum, amax, pg, probs, 0);
  k_gemm<<<dim3(50,126), 256, 0, stream>>>(hid_bf, W2T, b2, Ssum, amax, pg, probs, 1);
  k_scatter<<<3200, 256, 0, stream>>>(ext, a_all, pg, probs, amax);
  k_seqout <<<13, 256, 0, stream>>>(amax, seqs);
}